// Round 21
// baseline (79.649 us; speedup 1.0000x reference)
//
#include <hip/hip_runtime.h>

// Problem: B=4, C=256, C4=64, N=4096, f32 in/out.
//   Q = Wqk@x; V = Wv@x + b; E = Q^T Q / 8; A = softmax_rows(E); out = V @ A
// Fused: out[c,m] = sum_n V[c,n] * exp2(dot_nm - 12) * zi[n],
//        zi[n] = 1 / sum_m exp2(dot_nm - 12);  dot = log2e*E (Qt pre-scaled).
// R14 (kept): FRAG-BLOCKED Qt — contiguous 1-KB wave tile loads.
// R20 (kept): no u_kernel; V stored blocked f16; Zinv folded into av's bt.
// R21: TRIANGULAR Z. E is symmetric -> compute each 16x16 E-tile ONCE
// (33K tiles/batch vs 65.5K): row-sums credit Z[Tn], col-sums (2 shfl_xor
// over lg) credit Z[Tm]. Work unit (Tn, j): offsets d=16j+1..16j+16 mod 256
// (d=128 only for Tn<128; diag d=0 -> j=0). Every partial slot has exactly
// one writer; zf_kernel sums 8 row + 128 col partials in fixed order ->
// bitwise deterministic. Zcp partials (4 MiB f16, 2^-12-shifted) live in
// d_out's dead interval (av fully overwrites later). ws use: 4.56 MiB.

#define CC 256
#define C4C 64
#define NBATCH 4
#define NN 4096
#define QSCALE 0.42466089f   // sqrt(log2(e)/8)
#define SHIFT2 12.0f

typedef _Float16 f16;
typedef _Float16 half2v __attribute__((ext_vector_type(2)));
typedef _Float16 half4 __attribute__((ext_vector_type(4)));
typedef _Float16 half8 __attribute__((ext_vector_type(8)));
typedef __fp16 fp16x2 __attribute__((ext_vector_type(2)));
typedef float floatx4 __attribute__((ext_vector_type(4)));

static __device__ __forceinline__ half2v pkrtz(float a, float b) {
  fp16x2 r = __builtin_amdgcn_cvt_pkrtz(a, b);
  return __builtin_bit_cast(half2v, r);
}

// Load one 16-n tile's MFMA frag pair: lane l gets {row=l&15, k=8*(l>>4)+j}
// (dual-use as A- or B-frag: E = Q Q^T is symmetric in the stored layout)
#define LOADQ(T, A0, A1)                                                   \
  { const f16* p_ = Qb + (size_t)(T) * 1024 + l * 8;                       \
    A0 = *(const half8*)(p_); A1 = *(const half8*)(p_ + 512); }

// ---------------- QV: Q/V projections via MFMA (R20) -------------------------
#define XT_PITCH 264
__global__ __launch_bounds__(256) void qv_kernel(
    const float* __restrict__ x, const float* __restrict__ Wqk,
    const float* __restrict__ Wv, const float* __restrict__ bv,
    f16* __restrict__ Qtb, f16* __restrict__ V4)
{
  __shared__ __align__(16) f16 xt[32][XT_PITCH];
  const int b = blockIdx.y;
  const int n0 = blockIdx.x * 32;
  const int tid = threadIdx.x;

  {
    const int nq = tid & 7;
    const int cb = tid >> 3;
    const int c = cb * 8;
    const float* xp = x + (size_t)b * CC * NN + n0 + nq * 4;
    float4 r[8];
#pragma unroll
    for (int j = 0; j < 8; ++j)
      r[j] = *(const float4*)(xp + (size_t)(c + j) * NN);
#pragma unroll
    for (int s = 0; s < 4; ++s) {
      half8 h;
#pragma unroll
      for (int j = 0; j < 8; ++j) h[j] = (f16)(((const float*)&r[j])[s]);
      *(half8*)(&xt[nq * 4 + s][c]) = h;
    }
  }

  const int w = tid >> 6, l = tid & 63, lr = l & 15, lg = l >> 4;
  const float* Wsrc = (w < 2) ? Wqk : Wv;
  const int ocb = (w & 1) * 32;
  half8 af[2][8];
#pragma unroll
  for (int t = 0; t < 2; ++t) {
    const float* wp = Wsrc + (size_t)(ocb + t * 16 + lr) * CC + 8 * lg;
#pragma unroll
    for (int kk = 0; kk < 8; ++kk) {
      float4 wa = *(const float4*)(wp + kk * 32);
      float4 wb = *(const float4*)(wp + kk * 32 + 4);
      half8 h;
      h[0] = (f16)wa.x; h[1] = (f16)wa.y; h[2] = (f16)wa.z; h[3] = (f16)wa.w;
      h[4] = (f16)wb.x; h[5] = (f16)wb.y; h[6] = (f16)wb.z; h[7] = (f16)wb.w;
      af[t][kk] = h;
    }
  }

  __syncthreads();

  floatx4 acc[2][2] = {{{0.f,0.f,0.f,0.f},{0.f,0.f,0.f,0.f}},
                       {{0.f,0.f,0.f,0.f},{0.f,0.f,0.f,0.f}}};
#pragma unroll
  for (int nt = 0; nt < 2; ++nt) {
#pragma unroll
    for (int kk = 0; kk < 8; ++kk) {
      half8 bf = *(const half8*)(&xt[nt * 16 + lr][kk * 32 + 8 * lg]);
      acc[0][nt] = __builtin_amdgcn_mfma_f32_16x16x32_f16(af[0][kk], bf, acc[0][nt], 0, 0, 0);
      acc[1][nt] = __builtin_amdgcn_mfma_f32_16x16x32_f16(af[1][kk], bf, acc[1][nt], 0, 0, 0);
    }
  }

  if (w < 2) {
    // Q blocked write: oc = w*32+t*16+4lg+i -> kg=2t+(lg>>1)
#pragma unroll
    for (int t = 0; t < 2; ++t)
#pragma unroll
      for (int nt = 0; nt < 2; ++nt) {
        int T = (n0 >> 4) + nt;
        int kg = 2 * t + (lg >> 1);
        union { f16 h[4]; unsigned long long u; } q4;
#pragma unroll
        for (int i = 0; i < 4; ++i) q4.h[i] = (f16)(acc[t][nt][i] * QSCALE);
        *(unsigned long long*)(Qtb + (size_t)(b * 256 + T) * 1024 + w * 512
                               + (kg * 16 + lr) * 8 + (lg & 1) * 4) = q4.u;
      }
  } else {
    // V blocked f16 write: idx = (b*256+T)*1024 + oc*16 + lr
#pragma unroll
    for (int t = 0; t < 2; ++t)
#pragma unroll
      for (int nt = 0; nt < 2; ++nt) {
        int T = (n0 >> 4) + nt;
        int oc = (w - 2) * 32 + t * 16 + 4 * lg;
#pragma unroll
        for (int i = 0; i < 4; ++i)
          V4[(size_t)(b * 256 + T) * 1024 + (oc + i) * 16 + lr] =
              (f16)(acc[t][nt][i] + bv[oc + i]);
      }
  }
}

// ---------------- Z2: triangular E-tile sweep --------------------------------
// grid 2048 (XCD-swizzled) block 256 (4 waves, no LDS, no barriers).
// Wave unit (Tn, j): diag (j==0) + d = 16j+1..16j+16, Tm = (Tn+d)&255
// (skip d=128 when Tn>=128). Per tile: 2 MFMA (C=-12) -> 4 exp2 ->
// row-sums (regs) + col-sum (3 adds + 2 shfl_xor over lg) -> Zcp[d-1][b][Tm].
__global__ __launch_bounds__(256) void z2_kernel(
    const f16* __restrict__ Qtb, float* __restrict__ rowp,
    f16* __restrict__ Zcp)
{
  const int bx = blockIdx.x;
  const int xcd = bx & 7, slot = bx >> 3;       // slot 0..255
  const int b = xcd >> 1;                        // 2 XCDs per batch
  const int wu = ((xcd & 1) << 8) | slot;        // 0..511 per batch
  const int tid = threadIdx.x;
  const int w = tid >> 6, l = tid & 63, lr = l & 15, lg = l >> 4;
  const int unit = wu * 4 + w;                   // 0..2047
  const int Tn = unit >> 3;                      // 0..255
  const int j = unit & 7;                        // 0..7
  const f16* Qb = Qtb + (size_t)b * 256 * 1024;

  half8 a0, a1;
  LOADQ(Tn, a0, a1);
  float rs[4] = {0.f, 0.f, 0.f, 0.f};

  if (j == 0) {   // diagonal tile: row-sums only (col-sums would double count)
    floatx4 d = {-SHIFT2, -SHIFT2, -SHIFT2, -SHIFT2};
    d = __builtin_amdgcn_mfma_f32_16x16x32_f16(a0, a0, d, 0, 0, 0);
    d = __builtin_amdgcn_mfma_f32_16x16x32_f16(a1, a1, d, 0, 0, 0);
#pragma unroll
    for (int i = 0; i < 4; ++i) rs[i] += __builtin_amdgcn_exp2f(d[i]);
  }

#pragma unroll 2
  for (int dd = 1; dd <= 16; ++dd) {
    const int dgl = j * 16 + dd;                 // 1..128
    if (dgl == 128 && Tn >= 128) continue;       // wave-uniform
    const int Tm = (Tn + dgl) & 255;
    half8 b0, b1;
    LOADQ(Tm, b0, b1);
    floatx4 d = {-SHIFT2, -SHIFT2, -SHIFT2, -SHIFT2};
    d = __builtin_amdgcn_mfma_f32_16x16x32_f16(a0, b0, d, 0, 0, 0);
    d = __builtin_amdgcn_mfma_f32_16x16x32_f16(a1, b1, d, 0, 0, 0);
    float e0 = __builtin_amdgcn_exp2f(d[0]);
    float e1 = __builtin_amdgcn_exp2f(d[1]);
    float e2 = __builtin_amdgcn_exp2f(d[2]);
    float e3 = __builtin_amdgcn_exp2f(d[3]);
    rs[0] += e0; rs[1] += e1; rs[2] += e2; rs[3] += e3;
    float cs = (e0 + e1) + (e2 + e3);            // col-sum over this lane's rows
    cs += __shfl_xor(cs, 16);                    // sum over lg (rows 0..15)
    cs += __shfl_xor(cs, 32);
    if (lg == 0)
      Zcp[(size_t)(dgl - 1) * (NBATCH * NN) + b * NN + Tm * 16 + lr] = (f16)cs;
  }

  // row-sum reduce over lr (cols) and store single-writer partial
#pragma unroll
  for (int i = 0; i < 4; ++i) {
    float v = rs[i];
    v += __shfl_xor(v, 1); v += __shfl_xor(v, 2);
    v += __shfl_xor(v, 4); v += __shfl_xor(v, 8);
    rs[i] = v;
  }
  if (lr == 0) {
#pragma unroll
    for (int i = 0; i < 4; ++i)
      rowp[(size_t)j * (NBATCH * NN) + b * NN + Tn * 16 + 4 * lg + i] = rs[i];
  }
}

// ---------------- ZF: Zinv = 1 / (sum of 8 row + 128 col partials) -----------
// Fixed order -> deterministic. d=128 slot valid only for n >= 2048 (mod NN).
__global__ __launch_bounds__(256) void zf_kernel(
    const float* __restrict__ rowp, const f16* __restrict__ Zcp,
    float* __restrict__ Zinv)
{
  int i = blockIdx.x * 256 + threadIdx.x;   // 0..16383 (= b*NN + n)
  float s = 0.f;
#pragma unroll
  for (int k = 0; k < 8; ++k) s += rowp[(size_t)k * (NBATCH * NN) + i];
#pragma unroll 4
  for (int ds = 0; ds < 127; ++ds) s += (float)Zcp[(size_t)ds * (NBATCH * NN) + i];
  if ((i & (NN - 1)) >= 2048) s += (float)Zcp[(size_t)127 * (NBATCH * NN) + i];
  Zinv[i] = 1.0f / s;
}

// ---------------- PV pass (R20): blocked loads, Zinv fold, unroll 2 ----------
#define LOADV(NB, UA)                                                      \
  { const f16* up_ = Vb + (size_t)(NB) * 1024 + 4 * lg;                    \
    _Pragma("unroll")                                                      \
    for (int cs = 0; cs < 4; ++cs)                                         \
      UA[cs] = *(const half4*)(up_ + (16 * cs + lr) * 16); }

__global__ __launch_bounds__(512, 4) void av_kernel(
    const f16* __restrict__ Qtb, const f16* __restrict__ V4,
    const float* __restrict__ Zinv, float* __restrict__ Out)
{
  __shared__ float red[8][2][16][17];  // ~17.4 KB

  const int bx = blockIdx.x;
  const int xcd = bx & 7, slot = bx >> 3;          // slot 0..63
  const int b = xcd >> 1;                          // 2 XCDs per batch
  const int m0 = (((xcd & 1) << 6) | slot) * 32;   // 128 m-tiles per batch
  const int tid = threadIdx.x;
  const int w = tid >> 6;                          // 0..7
  const int l = tid & 63;
  const int lr = l & 15, lg = l >> 4;

  const f16* Qb = Qtb + (size_t)b * 256 * 1024;
  const f16* Vb = V4 + (size_t)b * 256 * 1024;
  const float* Zb = Zinv + b * NN;

  half8 bq[2][2];
  LOADQ((m0 >> 4), bq[0][0], bq[0][1]);
  LOADQ((m0 >> 4) + 1, bq[1][0], bq[1][1]);

  floatx4 o[4][2];
#pragma unroll
  for (int cs = 0; cs < 4; ++cs)
#pragma unroll
    for (int t = 0; t < 2; ++t) o[cs][t] = (floatx4){0.f, 0.f, 0.f, 0.f};

#pragma unroll 2
  for (int it = 0; it < 32; ++it) {
    const int T = it * 8 + w;                      // this wave's n-tile
    half8 a0, a1;
    LOADQ(T, a0, a1);
    half4 va[4];
    LOADV(T, va);
    const float4 zi = *(const float4*)(Zb + T * 16 + 4 * lg);

    floatx4 dA = {-SHIFT2, -SHIFT2, -SHIFT2, -SHIFT2};
    floatx4 dB = {-SHIFT2, -SHIFT2, -SHIFT2, -SHIFT2};
    dA = __builtin_amdgcn_mfma_f32_16x16x32_f16(a0, bq[0][0], dA, 0, 0, 0);
    dB = __builtin_amdgcn_mfma_f32_16x16x32_f16(a0, bq[1][0], dB, 0, 0, 0);
    dA = __builtin_amdgcn_mfma_f32_16x16x32_f16(a1, bq[0][1], dA, 0, 0, 0);
    dB = __builtin_amdgcn_mfma_f32_16x16x32_f16(a1, bq[1][1], dB, 0, 0, 0);

    half2v p0a = pkrtz(__builtin_amdgcn_exp2f(dA[0]) * zi.x,
                       __builtin_amdgcn_exp2f(dA[1]) * zi.y);
    half2v p0b = pkrtz(__builtin_amdgcn_exp2f(dA[2]) * zi.z,
                       __builtin_amdgcn_exp2f(dA[3]) * zi.w);
    half2v p1a = pkrtz(__builtin_amdgcn_exp2f(dB[0]) * zi.x,
                       __builtin_amdgcn_exp2f(dB[1]) * zi.y);
    half2v p1b = pkrtz(__builtin_amdgcn_exp2f(dB[2]) * zi.z,
                       __builtin_amdgcn_exp2f(dB[3]) * zi.w);
    half4 bt0 = {p0a[0], p0a[1], p0b[0], p0b[1]};
    half4 bt1 = {p1a[0], p1a[1], p1b[0], p1b[1]};
#pragma unroll
    for (int cs = 0; cs < 4; ++cs) {
      o[cs][0] = __builtin_amdgcn_mfma_f32_16x16x16f16(va[cs], bt0, o[cs][0], 0, 0, 0);
      o[cs][1] = __builtin_amdgcn_mfma_f32_16x16x16f16(va[cs], bt1, o[cs][1], 0, 0, 0);
    }
  }

  // ---- 8-wave reduction, fixed order: deterministic, direct stores ----
#pragma unroll 1
  for (int cs = 0; cs < 4; ++cs) {
    __syncthreads();
#pragma unroll
    for (int t = 0; t < 2; ++t)
#pragma unroll
      for (int i = 0; i < 4; ++i)
        red[w][t][4 * lg + i][lr] = o[cs][t][i];
    __syncthreads();
    const int t = tid >> 8;              // 0..1
    const int r = (tid >> 4) & 15;       // 0..15
    const int col = tid & 15;            // 0..15
    float ssum = 0.f;
#pragma unroll
    for (int ww = 0; ww < 8; ++ww) ssum += red[ww][t][r][col];
    Out[((size_t)b * C4C + cs * 16 + r) * NN + m0 + t * 16 + col] = ssum;
  }
}

// ---------------- launch ----------------
// ws layout (4.56 MiB):
//   Qtb  f16 [4][256][2][64][8] 2 MiB    @ 0        (frag-blocked Q)
//   V4   f16 [4][256][64][16]   2 MiB    @ 2 MiB    (blocked V, PV A-frag)
//   rowp f32 [8][4][4096]       512 KiB  @ 4 MiB
//   Zinv f32 [4][4096]          64 KiB   @ 4.5 MiB
// Zcp  f16 [128][4][4096] = 4 MiB lives in d_out (dead until av overwrites).
extern "C" void kernel_launch(void* const* d_in, const int* in_sizes, int n_in,
                              void* d_out, int out_size, void* d_ws, size_t ws_size,
                              hipStream_t stream)
{
  const float* x   = (const float*)d_in[0];
  const float* Wqk = (const float*)d_in[1];
  const float* Wv  = (const float*)d_in[2];
  const float* bv  = (const float*)d_in[3];
  float* out = (float*)d_out;

  char* ws = (char*)d_ws;
  f16*   Qtb  = (f16*)(ws);
  f16*   V4   = (f16*)(ws + (2u << 20));
  float* rowp = (float*)(ws + (4u << 20));
  float* Zinv = (float*)(ws + (4u << 20) + (512u << 10));
  f16*   Zcp  = (f16*)d_out;   // scratch in d_out's dead interval

  qv_kernel<<<dim3(128, 4), 256, 0, stream>>>(x, Wqk, Wv, bv, Qtb, V4);
  z2_kernel<<<dim3(2048), 256, 0, stream>>>(Qtb, rowp, Zcp);
  zf_kernel<<<dim3(64), 256, 0, stream>>>(rowp, Zcp, Zinv);
  av_kernel<<<dim3(512), 512, 0, stream>>>(Qtb, V4, Zinv, out);
}

// Round 22
// 64.466 us; speedup vs baseline: 1.2355x; 1.2355x over previous
//
#include <hip/hip_runtime.h>

// Problem: B=4, C=256, C4=64, N=4096, f32 in/out.
//   Q = Wqk@x; V = Wv@x + b; E = Q^T Q / 8; A = softmax_rows(E); out = V @ A
// Fused: out[c,m] = sum_n V[c,n] * exp2(dot_nm - 12) * (4096/Zraw[n]),
//        Zraw[n] = sum_m exp2(dot_nm);  dot = log2e*E (Qt pre-scaled).
// R14 (kept): FRAG-BLOCKED Qt — contiguous 1-KB wave tile loads.
// R20 (kept): no u_kernel; V blocked f16; Z-normalization folded into av's bt.
// R22: R21's triangular Z REVERTED (traded cheap compute for scarce memory
// traffic: 63 -> 80 us). zr dispatch DELETED: av computes
// zi = 4096 * v_rcp(Zp0[n]+Zp1[n]) inline (+32 B/iter L2 reads, ~12 VALU).
// 3 dispatches: qv -> z -> av.

#define CC 256
#define C4C 64
#define NBATCH 4
#define NN 4096
#define QSCALE 0.42466089f   // sqrt(log2(e)/8)
#define SHIFT2 12.0f

typedef _Float16 f16;
typedef _Float16 half2v __attribute__((ext_vector_type(2)));
typedef _Float16 half4 __attribute__((ext_vector_type(4)));
typedef _Float16 half8 __attribute__((ext_vector_type(8)));
typedef __fp16 fp16x2 __attribute__((ext_vector_type(2)));
typedef float floatx4 __attribute__((ext_vector_type(4)));

static __device__ __forceinline__ half2v pkrtz(float a, float b) {
  fp16x2 r = __builtin_amdgcn_cvt_pkrtz(a, b);
  return __builtin_bit_cast(half2v, r);
}

// Load one 16-n tile's MFMA frag pair: lane l gets {row=l&15, k=8*(l>>4)+j}
#define LOADQ(T, A0, A1)                                                   \
  { const f16* p_ = Qb + (size_t)(T) * 1024 + l * 8;                       \
    A0 = *(const half8*)(p_); A1 = *(const half8*)(p_ + 512); }

// ---------------- QV: Q/V projections via MFMA -------------------------------
// grid (128, 4) block 256 (4 waves). Block tile: 128 oc x 32 n, K=C=256.
// Q -> frag-blocked Qtb; V -> blocked f16 V4[b][T][c][16] (PV A-frag layout).
#define XT_PITCH 264
__global__ __launch_bounds__(256) void qv_kernel(
    const float* __restrict__ x, const float* __restrict__ Wqk,
    const float* __restrict__ Wv, const float* __restrict__ bv,
    f16* __restrict__ Qtb, f16* __restrict__ V4)
{
  __shared__ __align__(16) f16 xt[32][XT_PITCH];
  const int b = blockIdx.y;
  const int n0 = blockIdx.x * 32;
  const int tid = threadIdx.x;

  {
    const int nq = tid & 7;
    const int cb = tid >> 3;
    const int c = cb * 8;
    const float* xp = x + (size_t)b * CC * NN + n0 + nq * 4;
    float4 r[8];
#pragma unroll
    for (int j = 0; j < 8; ++j)
      r[j] = *(const float4*)(xp + (size_t)(c + j) * NN);
#pragma unroll
    for (int s = 0; s < 4; ++s) {
      half8 h;
#pragma unroll
      for (int j = 0; j < 8; ++j) h[j] = (f16)(((const float*)&r[j])[s]);
      *(half8*)(&xt[nq * 4 + s][c]) = h;
    }
  }

  const int w = tid >> 6, l = tid & 63, lr = l & 15, lg = l >> 4;
  const float* Wsrc = (w < 2) ? Wqk : Wv;
  const int ocb = (w & 1) * 32;
  half8 af[2][8];
#pragma unroll
  for (int t = 0; t < 2; ++t) {
    const float* wp = Wsrc + (size_t)(ocb + t * 16 + lr) * CC + 8 * lg;
#pragma unroll
    for (int kk = 0; kk < 8; ++kk) {
      float4 wa = *(const float4*)(wp + kk * 32);
      float4 wb = *(const float4*)(wp + kk * 32 + 4);
      half8 h;
      h[0] = (f16)wa.x; h[1] = (f16)wa.y; h[2] = (f16)wa.z; h[3] = (f16)wa.w;
      h[4] = (f16)wb.x; h[5] = (f16)wb.y; h[6] = (f16)wb.z; h[7] = (f16)wb.w;
      af[t][kk] = h;
    }
  }

  __syncthreads();

  floatx4 acc[2][2] = {{{0.f,0.f,0.f,0.f},{0.f,0.f,0.f,0.f}},
                       {{0.f,0.f,0.f,0.f},{0.f,0.f,0.f,0.f}}};
#pragma unroll
  for (int nt = 0; nt < 2; ++nt) {
#pragma unroll
    for (int kk = 0; kk < 8; ++kk) {
      half8 bf = *(const half8*)(&xt[nt * 16 + lr][kk * 32 + 8 * lg]);
      acc[0][nt] = __builtin_amdgcn_mfma_f32_16x16x32_f16(af[0][kk], bf, acc[0][nt], 0, 0, 0);
      acc[1][nt] = __builtin_amdgcn_mfma_f32_16x16x32_f16(af[1][kk], bf, acc[1][nt], 0, 0, 0);
    }
  }

  if (w < 2) {
    // Q blocked write: oc = w*32+t*16+4lg+i -> kg=2t+(lg>>1)
#pragma unroll
    for (int t = 0; t < 2; ++t)
#pragma unroll
      for (int nt = 0; nt < 2; ++nt) {
        int T = (n0 >> 4) + nt;
        int kg = 2 * t + (lg >> 1);
        union { f16 h[4]; unsigned long long u; } q4;
#pragma unroll
        for (int i = 0; i < 4; ++i) q4.h[i] = (f16)(acc[t][nt][i] * QSCALE);
        *(unsigned long long*)(Qtb + (size_t)(b * 256 + T) * 1024 + w * 512
                               + (kg * 16 + lr) * 8 + (lg & 1) * 4) = q4.u;
      }
  } else {
    // V blocked f16 write: idx = (b*256+T)*1024 + oc*16 + lr
#pragma unroll
    for (int t = 0; t < 2; ++t)
#pragma unroll
      for (int nt = 0; nt < 2; ++nt) {
        int T = (n0 >> 4) + nt;
        int oc = (w - 2) * 32 + t * 16 + 4 * lg;
#pragma unroll
        for (int i = 0; i < 4; ++i)
          V4[(size_t)(b * 256 + T) * 1024 + (oc + i) * 16 + lr] =
              (f16)(acc[t][nt][i] + bv[oc + i]);
      }
  }
}

// ---------------- Z pass (R18): 2-stage pipeline, blocked Qt loads -----------
#define Z_PRELOAD(TBEG)                                                    \
  { _Pragma("unroll")                                                      \
    for (int mt = 0; mt < 8; ++mt) {                                       \
      const f16* p_ = Qb + (size_t)((TBEG) + mt) * 1024 + l * 8;           \
      bb[mt][0] = *(const half8*)(p_);                                     \
      bb[mt][1] = *(const half8*)(p_ + 512);                               \
    } }

#define Z_E(MT, D0, D1)                                                    \
  { D0 = (floatx4){0.f,0.f,0.f,0.f}; D1 = (floatx4){0.f,0.f,0.f,0.f};      \
    D0 = __builtin_amdgcn_mfma_f32_16x16x32_f16(a[0][0], bb[MT][0], D0, 0, 0, 0); \
    D1 = __builtin_amdgcn_mfma_f32_16x16x32_f16(a[1][0], bb[MT][0], D1, 0, 0, 0); \
    D0 = __builtin_amdgcn_mfma_f32_16x16x32_f16(a[0][1], bb[MT][1], D0, 0, 0, 0); \
    D1 = __builtin_amdgcn_mfma_f32_16x16x32_f16(a[1][1], bb[MT][1], D1, 0, 0, 0); }

#define Z_SM(D0, D1)                                                       \
  { _Pragma("unroll")                                                      \
    for (int i = 0; i < 4; ++i) {                                          \
      rs[0][i] += __builtin_amdgcn_exp2f(D0[i]);                           \
      rs[1][i] += __builtin_amdgcn_exp2f(D1[i]); } }

#define Z_TILES17                                                          \
  Z_E(1, dB0, dB1); Z_SM(dA0, dA1);                                        \
  Z_E(2, dA0, dA1); Z_SM(dB0, dB1);                                        \
  Z_E(3, dB0, dB1); Z_SM(dA0, dA1);                                        \
  Z_E(4, dA0, dA1); Z_SM(dB0, dB1);                                        \
  Z_E(5, dB0, dB1); Z_SM(dA0, dA1);                                        \
  Z_E(6, dA0, dA1); Z_SM(dB0, dB1);                                        \
  Z_E(7, dB0, dB1); Z_SM(dA0, dA1);

__global__ __launch_bounds__(256) void z_kernel(
    const f16* __restrict__ Qtb, float* __restrict__ Zp)
{
  __shared__ float zl[4][32];
  const int bx = blockIdx.x;
  const int xcd = bx & 7, slot = bx >> 3;       // slot 0..127
  const int b = xcd >> 1;                        // 2 XCDs per batch
  const int wu = ((xcd & 1) << 7) | slot;        // 0..255 per batch
  const int n0 = (wu >> 1) * 32;                 // nb 0..127
  const int mh = wu & 1;                         // m half
  const int tid = threadIdx.x;
  const int w = tid >> 6, l = tid & 63, lr = l & 15, lg = l >> 4;
  const f16* Qb = Qtb + (size_t)b * 256 * 1024;

  half8 a[2][2];
  LOADQ((n0 >> 4), a[0][0], a[0][1]);
  LOADQ((n0 >> 4) + 1, a[1][0], a[1][1]);

  const int tstr = mh * 128 + w * 32;            // tile base (512 m = 32 tiles)
  half8 bb[8][2];
  floatx4 dA0, dA1, dB0, dB1;
  float rs[2][4] = {{0.f,0.f,0.f,0.f},{0.f,0.f,0.f,0.f}};

  Z_PRELOAD(tstr);
  Z_E(0, dA0, dA1);
  Z_TILES17;
#pragma unroll 1
  for (int mch = 1; mch < 4; ++mch) {
    Z_PRELOAD(tstr + mch * 8);
    Z_SM(dB0, dB1);
    Z_E(0, dA0, dA1);
    Z_TILES17;
  }
  Z_SM(dB0, dB1);

#pragma unroll
  for (int t = 0; t < 2; ++t)
#pragma unroll
    for (int i = 0; i < 4; ++i) {
      float v = rs[t][i];
      v += __shfl_xor(v, 1); v += __shfl_xor(v, 2);
      v += __shfl_xor(v, 4); v += __shfl_xor(v, 8);
      rs[t][i] = v;
    }
  if (lr == 0) {
#pragma unroll
    for (int t = 0; t < 2; ++t)
#pragma unroll
      for (int i = 0; i < 4; ++i)
        zl[w][16 * t + 4 * lg + i] = rs[t][i];
  }
  __syncthreads();
  if (tid < 32) {   // fixed-order cross-wave sum: deterministic
    float s = zl[0][tid] + zl[1][tid] + zl[2][tid] + zl[3][tid];
    Zp[(size_t)mh * NBATCH * NN + b * NN + n0 + tid] = s;
  }
}

// ---------------- PV pass: blocked loads, inline Zp reduce + rcp, unroll 2 ---
// grid 512 (XCD-swizzled) block 512 (8 waves, (512,4)). Block: 32 m, all n.
// Wave w: tiles w+8i, i=0..31. Per step: LOADQ + LOADV + 2x float4 Zp ->
//   zi = 4096*rcp(Zp0+Zp1) -> E-MFMA x4 (C=-12) -> exp2*zi -> pkrtz ->
//   PV-MFMA x8 (K=16). End: fixed-order 8-wave LDS reduce, direct stores.
#define LOADV(NB, UA)                                                      \
  { const f16* up_ = Vb + (size_t)(NB) * 1024 + 4 * lg;                    \
    _Pragma("unroll")                                                      \
    for (int cs = 0; cs < 4; ++cs)                                         \
      UA[cs] = *(const half4*)(up_ + (16 * cs + lr) * 16); }

__global__ __launch_bounds__(512, 4) void av_kernel(
    const f16* __restrict__ Qtb, const f16* __restrict__ V4,
    const float* __restrict__ Zp, float* __restrict__ Out)
{
  __shared__ float red[8][2][16][17];  // ~17.4 KB

  const int bx = blockIdx.x;
  const int xcd = bx & 7, slot = bx >> 3;          // slot 0..63
  const int b = xcd >> 1;                          // 2 XCDs per batch
  const int m0 = (((xcd & 1) << 6) | slot) * 32;   // 128 m-tiles per batch
  const int tid = threadIdx.x;
  const int w = tid >> 6;                          // 0..7
  const int l = tid & 63;
  const int lr = l & 15, lg = l >> 4;

  const f16* Qb = Qtb + (size_t)b * 256 * 1024;
  const f16* Vb = V4 + (size_t)b * 256 * 1024;
  const float* Zb0 = Zp + b * NN;                  // m-half 0 partial
  const float* Zb1 = Zp + (size_t)NBATCH * NN + b * NN;  // m-half 1 partial

  half8 bq[2][2];
  LOADQ((m0 >> 4), bq[0][0], bq[0][1]);
  LOADQ((m0 >> 4) + 1, bq[1][0], bq[1][1]);

  floatx4 o[4][2];
#pragma unroll
  for (int cs = 0; cs < 4; ++cs)
#pragma unroll
    for (int t = 0; t < 2; ++t) o[cs][t] = (floatx4){0.f, 0.f, 0.f, 0.f};

#pragma unroll 2
  for (int it = 0; it < 32; ++it) {
    const int T = it * 8 + w;                      // this wave's n-tile
    half8 a0, a1;
    LOADQ(T, a0, a1);
    half4 va[4];
    LOADV(T, va);
    const float4 z0 = *(const float4*)(Zb0 + T * 16 + 4 * lg);
    const float4 z1 = *(const float4*)(Zb1 + T * 16 + 4 * lg);
    float4 zi;
    zi.x = 4096.0f * __builtin_amdgcn_rcpf(z0.x + z1.x);
    zi.y = 4096.0f * __builtin_amdgcn_rcpf(z0.y + z1.y);
    zi.z = 4096.0f * __builtin_amdgcn_rcpf(z0.z + z1.z);
    zi.w = 4096.0f * __builtin_amdgcn_rcpf(z0.w + z1.w);

    floatx4 dA = {-SHIFT2, -SHIFT2, -SHIFT2, -SHIFT2};
    floatx4 dB = {-SHIFT2, -SHIFT2, -SHIFT2, -SHIFT2};
    dA = __builtin_amdgcn_mfma_f32_16x16x32_f16(a0, bq[0][0], dA, 0, 0, 0);
    dB = __builtin_amdgcn_mfma_f32_16x16x32_f16(a0, bq[1][0], dB, 0, 0, 0);
    dA = __builtin_amdgcn_mfma_f32_16x16x32_f16(a1, bq[0][1], dA, 0, 0, 0);
    dB = __builtin_amdgcn_mfma_f32_16x16x32_f16(a1, bq[1][1], dB, 0, 0, 0);

    half2v p0a = pkrtz(__builtin_amdgcn_exp2f(dA[0]) * zi.x,
                       __builtin_amdgcn_exp2f(dA[1]) * zi.y);
    half2v p0b = pkrtz(__builtin_amdgcn_exp2f(dA[2]) * zi.z,
                       __builtin_amdgcn_exp2f(dA[3]) * zi.w);
    half2v p1a = pkrtz(__builtin_amdgcn_exp2f(dB[0]) * zi.x,
                       __builtin_amdgcn_exp2f(dB[1]) * zi.y);
    half2v p1b = pkrtz(__builtin_amdgcn_exp2f(dB[2]) * zi.z,
                       __builtin_amdgcn_exp2f(dB[3]) * zi.w);
    half4 bt0 = {p0a[0], p0a[1], p0b[0], p0b[1]};
    half4 bt1 = {p1a[0], p1a[1], p1b[0], p1b[1]};
#pragma unroll
    for (int cs = 0; cs < 4; ++cs) {
      o[cs][0] = __builtin_amdgcn_mfma_f32_16x16x16f16(va[cs], bt0, o[cs][0], 0, 0, 0);
      o[cs][1] = __builtin_amdgcn_mfma_f32_16x16x16f16(va[cs], bt1, o[cs][1], 0, 0, 0);
    }
  }

  // ---- 8-wave reduction, fixed order: deterministic, direct stores ----
#pragma unroll 1
  for (int cs = 0; cs < 4; ++cs) {
    __syncthreads();
#pragma unroll
    for (int t = 0; t < 2; ++t)
#pragma unroll
      for (int i = 0; i < 4; ++i)
        red[w][t][4 * lg + i][lr] = o[cs][t][i];
    __syncthreads();
    const int t = tid >> 8;              // 0..1
    const int r = (tid >> 4) & 15;       // 0..15
    const int col = tid & 15;            // 0..15
    float ssum = 0.f;
#pragma unroll
    for (int ww = 0; ww < 8; ++ww) ssum += red[ww][t][r][col];
    Out[((size_t)b * C4C + cs * 16 + r) * NN + m0 + t * 16 + col] = ssum;
  }
}

// ---------------- launch ----------------
// ws layout (4.13 MiB, no aliasing):
//   Qtb  f16 [4][256][2][64][8] 2 MiB    @ 0        (frag-blocked Q)
//   V4   f16 [4][256][64][16]   2 MiB    @ 2 MiB    (blocked V, PV A-frag)
//   Zp   f32 [2][4][4096]       128 KiB  @ 4 MiB
extern "C" void kernel_launch(void* const* d_in, const int* in_sizes, int n_in,
                              void* d_out, int out_size, void* d_ws, size_t ws_size,
                              hipStream_t stream)
{
  const float* x   = (const float*)d_in[0];
  const float* Wqk = (const float*)d_in[1];
  const float* Wv  = (const float*)d_in[2];
  const float* bv  = (const float*)d_in[3];
  float* out = (float*)d_out;

  char* ws = (char*)d_ws;
  f16*   Qtb = (f16*)(ws);
  f16*   V4  = (f16*)(ws + (2u << 20));
  float* Zp  = (float*)(ws + (4u << 20));

  qv_kernel<<<dim3(128, 4), 256, 0, stream>>>(x, Wqk, Wv, bv, Qtb, V4);
  z_kernel<<<dim3(1024), 256, 0, stream>>>(Qtb, Zp);
  av_kernel<<<dim3(512), 512, 0, stream>>>(Qtb, V4, Zp, out);
}

// Round 23
// 61.215 us; speedup vs baseline: 1.3011x; 1.0531x over previous
//
#include <hip/hip_runtime.h>

// Problem: B=4, C=256, C4=64, N=4096, f32 in/out.
//   Q = Wqk@x; V = Wv@x + b; E = Q^T Q / 8; A = softmax_rows(E); out = V @ A
// Fused: out[c,m] = sum_n V[c,n] * exp2(dot_nm - 12) * Zinv[n],
//        Zinv[n] = 4096 / sum_m exp2(dot_nm);  dot = log2e*E (Qt pre-scaled).
// R14 (kept): FRAG-BLOCKED Qt — contiguous 1-KB wave tile loads.
// R20 (kept): no u_kernel; V blocked f16; Zinv folded into av's bt; av loads
// PRECOMPUTED zi (R22 showed inline rcp in av costs more than a zr dispatch).
// R23: zr folded into z — each z block covers the FULL m range (grid 512,
// wave streams 64 tiles) so the block-level reduce is the complete Z[n];
// z writes Zinv directly. 3 dispatches: qv -> z -> av. av byte-identical R20.

#define CC 256
#define C4C 64
#define NBATCH 4
#define NN 4096
#define QSCALE 0.42466089f   // sqrt(log2(e)/8)
#define SHIFT2 12.0f

typedef _Float16 f16;
typedef _Float16 half2v __attribute__((ext_vector_type(2)));
typedef _Float16 half4 __attribute__((ext_vector_type(4)));
typedef _Float16 half8 __attribute__((ext_vector_type(8)));
typedef __fp16 fp16x2 __attribute__((ext_vector_type(2)));
typedef float floatx4 __attribute__((ext_vector_type(4)));

static __device__ __forceinline__ half2v pkrtz(float a, float b) {
  fp16x2 r = __builtin_amdgcn_cvt_pkrtz(a, b);
  return __builtin_bit_cast(half2v, r);
}

// Load one 16-n tile's MFMA frag pair: lane l gets {row=l&15, k=8*(l>>4)+j}
#define LOADQ(T, A0, A1)                                                   \
  { const f16* p_ = Qb + (size_t)(T) * 1024 + l * 8;                       \
    A0 = *(const half8*)(p_); A1 = *(const half8*)(p_ + 512); }

// ---------------- QV: Q/V projections via MFMA -------------------------------
// grid (128, 4) block 256 (4 waves). Block tile: 128 oc x 32 n, K=C=256.
// Q -> frag-blocked Qtb; V -> blocked f16 V4[b][T][c][16] (PV A-frag layout).
#define XT_PITCH 264
__global__ __launch_bounds__(256) void qv_kernel(
    const float* __restrict__ x, const float* __restrict__ Wqk,
    const float* __restrict__ Wv, const float* __restrict__ bv,
    f16* __restrict__ Qtb, f16* __restrict__ V4)
{
  __shared__ __align__(16) f16 xt[32][XT_PITCH];
  const int b = blockIdx.y;
  const int n0 = blockIdx.x * 32;
  const int tid = threadIdx.x;

  {
    const int nq = tid & 7;
    const int cb = tid >> 3;
    const int c = cb * 8;
    const float* xp = x + (size_t)b * CC * NN + n0 + nq * 4;
    float4 r[8];
#pragma unroll
    for (int j = 0; j < 8; ++j)
      r[j] = *(const float4*)(xp + (size_t)(c + j) * NN);
#pragma unroll
    for (int s = 0; s < 4; ++s) {
      half8 h;
#pragma unroll
      for (int j = 0; j < 8; ++j) h[j] = (f16)(((const float*)&r[j])[s]);
      *(half8*)(&xt[nq * 4 + s][c]) = h;
    }
  }

  const int w = tid >> 6, l = tid & 63, lr = l & 15, lg = l >> 4;
  const float* Wsrc = (w < 2) ? Wqk : Wv;
  const int ocb = (w & 1) * 32;
  half8 af[2][8];
#pragma unroll
  for (int t = 0; t < 2; ++t) {
    const float* wp = Wsrc + (size_t)(ocb + t * 16 + lr) * CC + 8 * lg;
#pragma unroll
    for (int kk = 0; kk < 8; ++kk) {
      float4 wa = *(const float4*)(wp + kk * 32);
      float4 wb = *(const float4*)(wp + kk * 32 + 4);
      half8 h;
      h[0] = (f16)wa.x; h[1] = (f16)wa.y; h[2] = (f16)wa.z; h[3] = (f16)wa.w;
      h[4] = (f16)wb.x; h[5] = (f16)wb.y; h[6] = (f16)wb.z; h[7] = (f16)wb.w;
      af[t][kk] = h;
    }
  }

  __syncthreads();

  floatx4 acc[2][2] = {{{0.f,0.f,0.f,0.f},{0.f,0.f,0.f,0.f}},
                       {{0.f,0.f,0.f,0.f},{0.f,0.f,0.f,0.f}}};
#pragma unroll
  for (int nt = 0; nt < 2; ++nt) {
#pragma unroll
    for (int kk = 0; kk < 8; ++kk) {
      half8 bf = *(const half8*)(&xt[nt * 16 + lr][kk * 32 + 8 * lg]);
      acc[0][nt] = __builtin_amdgcn_mfma_f32_16x16x32_f16(af[0][kk], bf, acc[0][nt], 0, 0, 0);
      acc[1][nt] = __builtin_amdgcn_mfma_f32_16x16x32_f16(af[1][kk], bf, acc[1][nt], 0, 0, 0);
    }
  }

  if (w < 2) {
    // Q blocked write: oc = w*32+t*16+4lg+i -> kg=2t+(lg>>1)
#pragma unroll
    for (int t = 0; t < 2; ++t)
#pragma unroll
      for (int nt = 0; nt < 2; ++nt) {
        int T = (n0 >> 4) + nt;
        int kg = 2 * t + (lg >> 1);
        union { f16 h[4]; unsigned long long u; } q4;
#pragma unroll
        for (int i = 0; i < 4; ++i) q4.h[i] = (f16)(acc[t][nt][i] * QSCALE);
        *(unsigned long long*)(Qtb + (size_t)(b * 256 + T) * 1024 + w * 512
                               + (kg * 16 + lr) * 8 + (lg & 1) * 4) = q4.u;
      }
  } else {
    // V blocked f16 write: idx = (b*256+T)*1024 + oc*16 + lr
#pragma unroll
    for (int t = 0; t < 2; ++t)
#pragma unroll
      for (int nt = 0; nt < 2; ++nt) {
        int T = (n0 >> 4) + nt;
        int oc = (w - 2) * 32 + t * 16 + 4 * lg;
#pragma unroll
        for (int i = 0; i < 4; ++i)
          V4[(size_t)(b * 256 + T) * 1024 + (oc + i) * 16 + lr] =
              (f16)(acc[t][nt][i] + bv[oc + i]);
      }
  }
}

// ---------------- Z pass: full-m blocks, writes Zinv directly ----------------
// grid 512 (XCD-swizzled) block 256 (4 waves). Block: 32 n x ALL 4096 m.
// Wave w streams 64 m-tiles (tiles w*64..w*64+63, 8 chunks of 8 preloaded).
// Block reduce -> complete Z[n] -> Zinv = 4096/Z. No partials, no zr.
#define Z_PRELOAD(TBEG)                                                    \
  { _Pragma("unroll")                                                      \
    for (int mt = 0; mt < 8; ++mt) {                                       \
      const f16* p_ = Qb + (size_t)((TBEG) + mt) * 1024 + l * 8;           \
      bb[mt][0] = *(const half8*)(p_);                                     \
      bb[mt][1] = *(const half8*)(p_ + 512);                               \
    } }

#define Z_E(MT, D0, D1)                                                    \
  { D0 = (floatx4){0.f,0.f,0.f,0.f}; D1 = (floatx4){0.f,0.f,0.f,0.f};      \
    D0 = __builtin_amdgcn_mfma_f32_16x16x32_f16(a[0][0], bb[MT][0], D0, 0, 0, 0); \
    D1 = __builtin_amdgcn_mfma_f32_16x16x32_f16(a[1][0], bb[MT][0], D1, 0, 0, 0); \
    D0 = __builtin_amdgcn_mfma_f32_16x16x32_f16(a[0][1], bb[MT][1], D0, 0, 0, 0); \
    D1 = __builtin_amdgcn_mfma_f32_16x16x32_f16(a[1][1], bb[MT][1], D1, 0, 0, 0); }

#define Z_SM(D0, D1)                                                       \
  { _Pragma("unroll")                                                      \
    for (int i = 0; i < 4; ++i) {                                          \
      rs[0][i] += __builtin_amdgcn_exp2f(D0[i]);                           \
      rs[1][i] += __builtin_amdgcn_exp2f(D1[i]); } }

#define Z_TILES17                                                          \
  Z_E(1, dB0, dB1); Z_SM(dA0, dA1);                                        \
  Z_E(2, dA0, dA1); Z_SM(dB0, dB1);                                        \
  Z_E(3, dB0, dB1); Z_SM(dA0, dA1);                                        \
  Z_E(4, dA0, dA1); Z_SM(dB0, dB1);                                        \
  Z_E(5, dB0, dB1); Z_SM(dA0, dA1);                                        \
  Z_E(6, dA0, dA1); Z_SM(dB0, dB1);                                        \
  Z_E(7, dB0, dB1); Z_SM(dA0, dA1);

__global__ __launch_bounds__(256) void z_kernel(
    const f16* __restrict__ Qtb, float* __restrict__ Zinv)
{
  __shared__ float zl[4][32];
  const int bx = blockIdx.x;
  const int xcd = bx & 7, slot = bx >> 3;       // slot 0..63
  const int b = xcd >> 1;                        // 2 XCDs per batch
  const int wu = ((xcd & 1) << 6) | slot;        // 0..127 per batch: n-group
  const int n0 = wu * 32;
  const int tid = threadIdx.x;
  const int w = tid >> 6, l = tid & 63, lr = l & 15, lg = l >> 4;
  const f16* Qb = Qtb + (size_t)b * 256 * 1024;

  half8 a[2][2];
  LOADQ((n0 >> 4), a[0][0], a[0][1]);
  LOADQ((n0 >> 4) + 1, a[1][0], a[1][1]);

  const int tstr = w * 64;                       // wave's 64-tile m strip
  half8 bb[8][2];
  floatx4 dA0, dA1, dB0, dB1;
  float rs[2][4] = {{0.f,0.f,0.f,0.f},{0.f,0.f,0.f,0.f}};

  Z_PRELOAD(tstr);
  Z_E(0, dA0, dA1);
  Z_TILES17;
#pragma unroll 1
  for (int mch = 1; mch < 8; ++mch) {
    Z_PRELOAD(tstr + mch * 8);
    Z_SM(dB0, dB1);
    Z_E(0, dA0, dA1);
    Z_TILES17;
  }
  Z_SM(dB0, dB1);

#pragma unroll
  for (int t = 0; t < 2; ++t)
#pragma unroll
    for (int i = 0; i < 4; ++i) {
      float v = rs[t][i];
      v += __shfl_xor(v, 1); v += __shfl_xor(v, 2);
      v += __shfl_xor(v, 4); v += __shfl_xor(v, 8);
      rs[t][i] = v;
    }
  if (lr == 0) {
#pragma unroll
    for (int t = 0; t < 2; ++t)
#pragma unroll
      for (int i = 0; i < 4; ++i)
        zl[w][16 * t + 4 * lg + i] = rs[t][i];
  }
  __syncthreads();
  if (tid < 32) {   // fixed-order cross-wave sum -> complete Z -> Zinv
    float s = zl[0][tid] + zl[1][tid] + zl[2][tid] + zl[3][tid];
    Zinv[b * NN + n0 + tid] = 4096.0f / s;
  }
}

// ---------------- PV pass (R20 exact): blocked loads, zi fold, unroll 2 ------
#define LOADV(NB, UA)                                                      \
  { const f16* up_ = Vb + (size_t)(NB) * 1024 + 4 * lg;                    \
    _Pragma("unroll")                                                      \
    for (int cs = 0; cs < 4; ++cs)                                         \
      UA[cs] = *(const half4*)(up_ + (16 * cs + lr) * 16); }

__global__ __launch_bounds__(512, 4) void av_kernel(
    const f16* __restrict__ Qtb, const f16* __restrict__ V4,
    const float* __restrict__ Zinv, float* __restrict__ Out)
{
  __shared__ float red[8][2][16][17];  // ~17.4 KB

  const int bx = blockIdx.x;
  const int xcd = bx & 7, slot = bx >> 3;          // slot 0..63
  const int b = xcd >> 1;                          // 2 XCDs per batch
  const int m0 = (((xcd & 1) << 6) | slot) * 32;   // 128 m-tiles per batch
  const int tid = threadIdx.x;
  const int w = tid >> 6;                          // 0..7
  const int l = tid & 63;
  const int lr = l & 15, lg = l >> 4;

  const f16* Qb = Qtb + (size_t)b * 256 * 1024;
  const f16* Vb = V4 + (size_t)b * 256 * 1024;
  const float* Zb = Zinv + b * NN;

  half8 bq[2][2];
  LOADQ((m0 >> 4), bq[0][0], bq[0][1]);
  LOADQ((m0 >> 4) + 1, bq[1][0], bq[1][1]);

  floatx4 o[4][2];
#pragma unroll
  for (int cs = 0; cs < 4; ++cs)
#pragma unroll
    for (int t = 0; t < 2; ++t) o[cs][t] = (floatx4){0.f, 0.f, 0.f, 0.f};

#pragma unroll 2
  for (int it = 0; it < 32; ++it) {
    const int T = it * 8 + w;                      // this wave's n-tile
    half8 a0, a1;
    LOADQ(T, a0, a1);
    half4 va[4];
    LOADV(T, va);
    const float4 zi = *(const float4*)(Zb + T * 16 + 4 * lg);

    floatx4 dA = {-SHIFT2, -SHIFT2, -SHIFT2, -SHIFT2};
    floatx4 dB = {-SHIFT2, -SHIFT2, -SHIFT2, -SHIFT2};
    dA = __builtin_amdgcn_mfma_f32_16x16x32_f16(a0, bq[0][0], dA, 0, 0, 0);
    dB = __builtin_amdgcn_mfma_f32_16x16x32_f16(a0, bq[1][0], dB, 0, 0, 0);
    dA = __builtin_amdgcn_mfma_f32_16x16x32_f16(a1, bq[0][1], dA, 0, 0, 0);
    dB = __builtin_amdgcn_mfma_f32_16x16x32_f16(a1, bq[1][1], dB, 0, 0, 0);

    half2v p0a = pkrtz(__builtin_amdgcn_exp2f(dA[0]) * zi.x,
                       __builtin_amdgcn_exp2f(dA[1]) * zi.y);
    half2v p0b = pkrtz(__builtin_amdgcn_exp2f(dA[2]) * zi.z,
                       __builtin_amdgcn_exp2f(dA[3]) * zi.w);
    half2v p1a = pkrtz(__builtin_amdgcn_exp2f(dB[0]) * zi.x,
                       __builtin_amdgcn_exp2f(dB[1]) * zi.y);
    half2v p1b = pkrtz(__builtin_amdgcn_exp2f(dB[2]) * zi.z,
                       __builtin_amdgcn_exp2f(dB[3]) * zi.w);
    half4 bt0 = {p0a[0], p0a[1], p0b[0], p0b[1]};
    half4 bt1 = {p1a[0], p1a[1], p1b[0], p1b[1]};
#pragma unroll
    for (int cs = 0; cs < 4; ++cs) {
      o[cs][0] = __builtin_amdgcn_mfma_f32_16x16x16f16(va[cs], bt0, o[cs][0], 0, 0, 0);
      o[cs][1] = __builtin_amdgcn_mfma_f32_16x16x16f16(va[cs], bt1, o[cs][1], 0, 0, 0);
    }
  }

  // ---- 8-wave reduction, fixed order: deterministic, direct stores ----
#pragma unroll 1
  for (int cs = 0; cs < 4; ++cs) {
    __syncthreads();
#pragma unroll
    for (int t = 0; t < 2; ++t)
#pragma unroll
      for (int i = 0; i < 4; ++i)
        red[w][t][4 * lg + i][lr] = o[cs][t][i];
    __syncthreads();
    const int t = tid >> 8;              // 0..1
    const int r = (tid >> 4) & 15;       // 0..15
    const int col = tid & 15;            // 0..15
    float ssum = 0.f;
#pragma unroll
    for (int ww = 0; ww < 8; ++ww) ssum += red[ww][t][r][col];
    Out[((size_t)b * C4C + cs * 16 + r) * NN + m0 + t * 16 + col] = ssum;
  }
}

// ---------------- launch ----------------
// ws layout (4.06 MiB, no aliasing):
//   Qtb  f16 [4][256][2][64][8] 2 MiB    @ 0        (frag-blocked Q)
//   V4   f16 [4][256][64][16]   2 MiB    @ 2 MiB    (blocked V, PV A-frag)
//   Zinv f32 [4][4096]          64 KiB   @ 4 MiB
extern "C" void kernel_launch(void* const* d_in, const int* in_sizes, int n_in,
                              void* d_out, int out_size, void* d_ws, size_t ws_size,
                              hipStream_t stream)
{
  const float* x   = (const float*)d_in[0];
  const float* Wqk = (const float*)d_in[1];
  const float* Wv  = (const float*)d_in[2];
  const float* bv  = (const float*)d_in[3];
  float* out = (float*)d_out;

  char* ws = (char*)d_ws;
  f16*   Qtb  = (f16*)(ws);
  f16*   V4   = (f16*)(ws + (2u << 20));
  float* Zinv = (float*)(ws + (4u << 20));

  qv_kernel<<<dim3(128, 4), 256, 0, stream>>>(x, Wqk, Wv, bv, Qtb, V4);
  z_kernel<<<dim3(512), 256, 0, stream>>>(Qtb, Zinv);
  av_kernel<<<dim3(512), 512, 0, stream>>>(Qtb, V4, Zinv, out);
}

// Round 24
// 60.504 us; speedup vs baseline: 1.3164x; 1.0117x over previous
//
#include <hip/hip_runtime.h>

// Problem: B=4, C=256, C4=64, N=4096, f32 in/out.
//   Q = Wqk@x; V = Wv@x + b; E = Q^T Q / 8; A = softmax_rows(E); out = V @ A
// Fused: out[c,m] = sum_n V[c,n] * exp2(dot_nm - 12) * Zinv[n],
//        Zinv[n] = 4096 / sum_m exp2(dot_nm);  dot = log2e*E (Qt pre-scaled).
// R14 (kept): FRAG-BLOCKED Qt — contiguous 1-KB wave tile loads.
// R20 (kept): no u_kernel; V blocked f16; precomputed Zinv folded into av bt.
// R23 (kept): z writes Zinv directly (full-m blocks); 3 dispatches.
// R24: z 64-n x full-m blocks, 8 waves (grid 256): per-wave m-work unchanged
// (32 tiles x 8 MFMA vs 64 x 4) but Qt stream HALVES (256 -> 128 MB of L1
// lines). R19's pitfall (halved per-wave work) avoided. qv/av identical R23.

#define CC 256
#define C4C 64
#define NBATCH 4
#define NN 4096
#define QSCALE 0.42466089f   // sqrt(log2(e)/8)
#define SHIFT2 12.0f

typedef _Float16 f16;
typedef _Float16 half2v __attribute__((ext_vector_type(2)));
typedef _Float16 half4 __attribute__((ext_vector_type(4)));
typedef _Float16 half8 __attribute__((ext_vector_type(8)));
typedef __fp16 fp16x2 __attribute__((ext_vector_type(2)));
typedef float floatx4 __attribute__((ext_vector_type(4)));

static __device__ __forceinline__ half2v pkrtz(float a, float b) {
  fp16x2 r = __builtin_amdgcn_cvt_pkrtz(a, b);
  return __builtin_bit_cast(half2v, r);
}

// Load one 16-n tile's MFMA frag pair: lane l gets {row=l&15, k=8*(l>>4)+j}
#define LOADQ(T, A0, A1)                                                   \
  { const f16* p_ = Qb + (size_t)(T) * 1024 + l * 8;                       \
    A0 = *(const half8*)(p_); A1 = *(const half8*)(p_ + 512); }

// ---------------- QV: Q/V projections via MFMA -------------------------------
// grid (128, 4) block 256 (4 waves). Block tile: 128 oc x 32 n, K=C=256.
// Q -> frag-blocked Qtb; V -> blocked f16 V4[b][T][c][16] (PV A-frag layout).
#define XT_PITCH 264
__global__ __launch_bounds__(256) void qv_kernel(
    const float* __restrict__ x, const float* __restrict__ Wqk,
    const float* __restrict__ Wv, const float* __restrict__ bv,
    f16* __restrict__ Qtb, f16* __restrict__ V4)
{
  __shared__ __align__(16) f16 xt[32][XT_PITCH];
  const int b = blockIdx.y;
  const int n0 = blockIdx.x * 32;
  const int tid = threadIdx.x;

  {
    const int nq = tid & 7;
    const int cb = tid >> 3;
    const int c = cb * 8;
    const float* xp = x + (size_t)b * CC * NN + n0 + nq * 4;
    float4 r[8];
#pragma unroll
    for (int j = 0; j < 8; ++j)
      r[j] = *(const float4*)(xp + (size_t)(c + j) * NN);
#pragma unroll
    for (int s = 0; s < 4; ++s) {
      half8 h;
#pragma unroll
      for (int j = 0; j < 8; ++j) h[j] = (f16)(((const float*)&r[j])[s]);
      *(half8*)(&xt[nq * 4 + s][c]) = h;
    }
  }

  const int w = tid >> 6, l = tid & 63, lr = l & 15, lg = l >> 4;
  const float* Wsrc = (w < 2) ? Wqk : Wv;
  const int ocb = (w & 1) * 32;
  half8 af[2][8];
#pragma unroll
  for (int t = 0; t < 2; ++t) {
    const float* wp = Wsrc + (size_t)(ocb + t * 16 + lr) * CC + 8 * lg;
#pragma unroll
    for (int kk = 0; kk < 8; ++kk) {
      float4 wa = *(const float4*)(wp + kk * 32);
      float4 wb = *(const float4*)(wp + kk * 32 + 4);
      half8 h;
      h[0] = (f16)wa.x; h[1] = (f16)wa.y; h[2] = (f16)wa.z; h[3] = (f16)wa.w;
      h[4] = (f16)wb.x; h[5] = (f16)wb.y; h[6] = (f16)wb.z; h[7] = (f16)wb.w;
      af[t][kk] = h;
    }
  }

  __syncthreads();

  floatx4 acc[2][2] = {{{0.f,0.f,0.f,0.f},{0.f,0.f,0.f,0.f}},
                       {{0.f,0.f,0.f,0.f},{0.f,0.f,0.f,0.f}}};
#pragma unroll
  for (int nt = 0; nt < 2; ++nt) {
#pragma unroll
    for (int kk = 0; kk < 8; ++kk) {
      half8 bf = *(const half8*)(&xt[nt * 16 + lr][kk * 32 + 8 * lg]);
      acc[0][nt] = __builtin_amdgcn_mfma_f32_16x16x32_f16(af[0][kk], bf, acc[0][nt], 0, 0, 0);
      acc[1][nt] = __builtin_amdgcn_mfma_f32_16x16x32_f16(af[1][kk], bf, acc[1][nt], 0, 0, 0);
    }
  }

  if (w < 2) {
    // Q blocked write: oc = w*32+t*16+4lg+i -> kg=2t+(lg>>1)
#pragma unroll
    for (int t = 0; t < 2; ++t)
#pragma unroll
      for (int nt = 0; nt < 2; ++nt) {
        int T = (n0 >> 4) + nt;
        int kg = 2 * t + (lg >> 1);
        union { f16 h[4]; unsigned long long u; } q4;
#pragma unroll
        for (int i = 0; i < 4; ++i) q4.h[i] = (f16)(acc[t][nt][i] * QSCALE);
        *(unsigned long long*)(Qtb + (size_t)(b * 256 + T) * 1024 + w * 512
                               + (kg * 16 + lr) * 8 + (lg & 1) * 4) = q4.u;
      }
  } else {
    // V blocked f16 write: idx = (b*256+T)*1024 + oc*16 + lr
#pragma unroll
    for (int t = 0; t < 2; ++t)
#pragma unroll
      for (int nt = 0; nt < 2; ++nt) {
        int T = (n0 >> 4) + nt;
        int oc = (w - 2) * 32 + t * 16 + 4 * lg;
#pragma unroll
        for (int i = 0; i < 4; ++i)
          V4[(size_t)(b * 256 + T) * 1024 + (oc + i) * 16 + lr] =
              (f16)(acc[t][nt][i] + bv[oc + i]);
      }
  }
}

// ---------------- Z pass: 64-n x full-m blocks, 8 waves, Zinv direct ---------
// grid 256 (XCD-swizzled) block 512 (8 waves). Block: 64 n (a[4][2] hoisted)
// x ALL 4096 m. Wave w streams 32 m-tiles (4 chunks of 8 preloaded), 8 MFMA
// per tile. Block reduce over 8 waves -> complete Z[n] -> Zinv = 4096/Z.
__global__ __launch_bounds__(512) void z_kernel(
    const f16* __restrict__ Qtb, float* __restrict__ Zinv)
{
  __shared__ float zl[8][64];
  const int bx = blockIdx.x;
  const int xcd = bx & 7, slot = bx >> 3;       // slot 0..31
  const int b = xcd >> 1;                        // 2 XCDs per batch
  const int wu = ((xcd & 1) << 5) | slot;        // 0..63 per batch: n-group
  const int n0t = wu * 4;                        // n-tile base (64 n)
  const int tid = threadIdx.x;
  const int w = tid >> 6, l = tid & 63, lr = l & 15, lg = l >> 4;
  const f16* Qb = Qtb + (size_t)b * 256 * 1024;

  half8 a[4][2];
#pragma unroll
  for (int t = 0; t < 4; ++t) LOADQ(n0t + t, a[t][0], a[t][1]);

  const int tstr = w * 32;                       // wave's 32-tile m strip
  float rs[4][4];
#pragma unroll
  for (int t = 0; t < 4; ++t)
#pragma unroll
    for (int i = 0; i < 4; ++i) rs[t][i] = 0.f;

#pragma unroll 1
  for (int ch = 0; ch < 4; ++ch) {
    half8 bb[8][2];
#pragma unroll
    for (int mt = 0; mt < 8; ++mt) {
      const f16* p_ = Qb + (size_t)(tstr + ch * 8 + mt) * 1024 + l * 8;
      bb[mt][0] = *(const half8*)(p_);
      bb[mt][1] = *(const half8*)(p_ + 512);
    }
#pragma unroll
    for (int mt = 0; mt < 8; ++mt) {
      floatx4 d[4];
#pragma unroll
      for (int t = 0; t < 4; ++t) {
        d[t] = (floatx4){0.f, 0.f, 0.f, 0.f};
        d[t] = __builtin_amdgcn_mfma_f32_16x16x32_f16(a[t][0], bb[mt][0], d[t], 0, 0, 0);
        d[t] = __builtin_amdgcn_mfma_f32_16x16x32_f16(a[t][1], bb[mt][1], d[t], 0, 0, 0);
      }
#pragma unroll
      for (int t = 0; t < 4; ++t)
#pragma unroll
        for (int i = 0; i < 4; ++i)
          rs[t][i] += __builtin_amdgcn_exp2f(d[t][i]);
    }
  }

#pragma unroll
  for (int t = 0; t < 4; ++t)
#pragma unroll
    for (int i = 0; i < 4; ++i) {
      float v = rs[t][i];
      v += __shfl_xor(v, 1); v += __shfl_xor(v, 2);
      v += __shfl_xor(v, 4); v += __shfl_xor(v, 8);
      rs[t][i] = v;
    }
  if (lr == 0) {
#pragma unroll
    for (int t = 0; t < 4; ++t)
#pragma unroll
      for (int i = 0; i < 4; ++i)
        zl[w][16 * t + 4 * lg + i] = rs[t][i];
  }
  __syncthreads();
  if (tid < 64) {   // fixed-order 8-wave sum -> complete Z -> Zinv
    float s = 0.f;
#pragma unroll
    for (int ww = 0; ww < 8; ++ww) s += zl[ww][tid];
    Zinv[b * NN + n0t * 16 + tid] = 4096.0f / s;
  }
}

// ---------------- PV pass (R20 exact): blocked loads, zi fold, unroll 2 ------
#define LOADV(NB, UA)                                                      \
  { const f16* up_ = Vb + (size_t)(NB) * 1024 + 4 * lg;                    \
    _Pragma("unroll")                                                      \
    for (int cs = 0; cs < 4; ++cs)                                         \
      UA[cs] = *(const half4*)(up_ + (16 * cs + lr) * 16); }

__global__ __launch_bounds__(512, 4) void av_kernel(
    const f16* __restrict__ Qtb, const f16* __restrict__ V4,
    const float* __restrict__ Zinv, float* __restrict__ Out)
{
  __shared__ float red[8][2][16][17];  // ~17.4 KB

  const int bx = blockIdx.x;
  const int xcd = bx & 7, slot = bx >> 3;          // slot 0..63
  const int b = xcd >> 1;                          // 2 XCDs per batch
  const int m0 = (((xcd & 1) << 6) | slot) * 32;   // 128 m-tiles per batch
  const int tid = threadIdx.x;
  const int w = tid >> 6;                          // 0..7
  const int l = tid & 63;
  const int lr = l & 15, lg = l >> 4;

  const f16* Qb = Qtb + (size_t)b * 256 * 1024;
  const f16* Vb = V4 + (size_t)b * 256 * 1024;
  const float* Zb = Zinv + b * NN;

  half8 bq[2][2];
  LOADQ((m0 >> 4), bq[0][0], bq[0][1]);
  LOADQ((m0 >> 4) + 1, bq[1][0], bq[1][1]);

  floatx4 o[4][2];
#pragma unroll
  for (int cs = 0; cs < 4; ++cs)
#pragma unroll
    for (int t = 0; t < 2; ++t) o[cs][t] = (floatx4){0.f, 0.f, 0.f, 0.f};

#pragma unroll 2
  for (int it = 0; it < 32; ++it) {
    const int T = it * 8 + w;                      // this wave's n-tile
    half8 a0, a1;
    LOADQ(T, a0, a1);
    half4 va[4];
    LOADV(T, va);
    const float4 zi = *(const float4*)(Zb + T * 16 + 4 * lg);

    floatx4 dA = {-SHIFT2, -SHIFT2, -SHIFT2, -SHIFT2};
    floatx4 dB = {-SHIFT2, -SHIFT2, -SHIFT2, -SHIFT2};
    dA = __builtin_amdgcn_mfma_f32_16x16x32_f16(a0, bq[0][0], dA, 0, 0, 0);
    dB = __builtin_amdgcn_mfma_f32_16x16x32_f16(a0, bq[1][0], dB, 0, 0, 0);
    dA = __builtin_amdgcn_mfma_f32_16x16x32_f16(a1, bq[0][1], dA, 0, 0, 0);
    dB = __builtin_amdgcn_mfma_f32_16x16x32_f16(a1, bq[1][1], dB, 0, 0, 0);

    half2v p0a = pkrtz(__builtin_amdgcn_exp2f(dA[0]) * zi.x,
                       __builtin_amdgcn_exp2f(dA[1]) * zi.y);
    half2v p0b = pkrtz(__builtin_amdgcn_exp2f(dA[2]) * zi.z,
                       __builtin_amdgcn_exp2f(dA[3]) * zi.w);
    half2v p1a = pkrtz(__builtin_amdgcn_exp2f(dB[0]) * zi.x,
                       __builtin_amdgcn_exp2f(dB[1]) * zi.y);
    half2v p1b = pkrtz(__builtin_amdgcn_exp2f(dB[2]) * zi.z,
                       __builtin_amdgcn_exp2f(dB[3]) * zi.w);
    half4 bt0 = {p0a[0], p0a[1], p0b[0], p0b[1]};
    half4 bt1 = {p1a[0], p1a[1], p1b[0], p1b[1]};
#pragma unroll
    for (int cs = 0; cs < 4; ++cs) {
      o[cs][0] = __builtin_amdgcn_mfma_f32_16x16x16f16(va[cs], bt0, o[cs][0], 0, 0, 0);
      o[cs][1] = __builtin_amdgcn_mfma_f32_16x16x16f16(va[cs], bt1, o[cs][1], 0, 0, 0);
    }
  }

  // ---- 8-wave reduction, fixed order: deterministic, direct stores ----
#pragma unroll 1
  for (int cs = 0; cs < 4; ++cs) {
    __syncthreads();
#pragma unroll
    for (int t = 0; t < 2; ++t)
#pragma unroll
      for (int i = 0; i < 4; ++i)
        red[w][t][4 * lg + i][lr] = o[cs][t][i];
    __syncthreads();
    const int t = tid >> 8;              // 0..1
    const int r = (tid >> 4) & 15;       // 0..15
    const int col = tid & 15;            // 0..15
    float ssum = 0.f;
#pragma unroll
    for (int ww = 0; ww < 8; ++ww) ssum += red[ww][t][r][col];
    Out[((size_t)b * C4C + cs * 16 + r) * NN + m0 + t * 16 + col] = ssum;
  }
}

// ---------------- launch ----------------
// ws layout (4.06 MiB, no aliasing):
//   Qtb  f16 [4][256][2][64][8] 2 MiB    @ 0        (frag-blocked Q)
//   V4   f16 [4][256][64][16]   2 MiB    @ 2 MiB    (blocked V, PV A-frag)
//   Zinv f32 [4][4096]          64 KiB   @ 4 MiB
extern "C" void kernel_launch(void* const* d_in, const int* in_sizes, int n_in,
                              void* d_out, int out_size, void* d_ws, size_t ws_size,
                              hipStream_t stream)
{
  const float* x   = (const float*)d_in[0];
  const float* Wqk = (const float*)d_in[1];
  const float* Wv  = (const float*)d_in[2];
  const float* bv  = (const float*)d_in[3];
  float* out = (float*)d_out;

  char* ws = (char*)d_ws;
  f16*   Qtb  = (f16*)(ws);
  f16*   V4   = (f16*)(ws + (2u << 20));
  float* Zinv = (float*)(ws + (4u << 20));

  qv_kernel<<<dim3(128, 4), 256, 0, stream>>>(x, Wqk, Wv, bv, Qtb, V4);
  z_kernel<<<dim3(256), 512, 0, stream>>>(Qtb, Zinv);
  av_kernel<<<dim3(512), 512, 0, stream>>>(Qtb, V4, Zinv, out);
}